// Round 1
// baseline (1186.146 us; speedup 1.0000x reference)
//
#include <hip/hip_runtime.h>
#include <math.h>

// Problem constants
// B=128, K=64, M=2048, QD=128, AD=128, H=256, C=32
// out: y (128*2048*3 = 786432) | type_logits (128*2048*32 = 8388608) | weight_logits (262144)

__device__ __forceinline__ float gelu_f(float x) {
    return 0.5f * x * (1.0f + erff(x * 0.70710678118654752f));
}

// ---------------- prep kernels ----------------

// inv[b,k] = ||g[b,k,:]||  (8192 values)
__global__ void k_inv(const float* __restrict__ g, float* __restrict__ invg) {
    int idx = blockIdx.x * blockDim.x + threadIdx.x; // 8192
    const float* p = g + idx * 3;
    invg[idx] = sqrtf(p[0]*p[0] + p[1]*p[1] + p[2]*p[2]);
}

// v[e] = sum_d qW[d,e]*kW[d] ; s0 = qb.kW
__global__ void k_v(const float* __restrict__ qW, const float* __restrict__ qb,
                    const float* __restrict__ kW, float* __restrict__ vg,
                    float* __restrict__ s0g) {
    int e = threadIdx.x; // 128 threads
    float acc = 0.f;
    for (int d = 0; d < 128; ++d) acc += qW[d*128 + e] * kW[d];
    vg[e] = acc;
    if (e == 0) {
        float s = 0.f;
        for (int d = 0; d < 128; ++d) s += qb[d] * kW[d];
        *s0g = s;
    }
}

// a[m] = (query[m].v + s0) / sqrt(128)
__global__ void k_a(const float* __restrict__ query, const float* __restrict__ vg,
                    const float* __restrict__ s0g, float* __restrict__ ag) {
    __shared__ float vs[128];
    int tid = threadIdx.x;
    if (tid < 128) vs[tid] = vg[tid];
    __syncthreads();
    int m = blockIdx.x * blockDim.x + tid; // 2048 total
    const float* q = query + m * 128;
    float acc = *s0g;
    for (int e = 0; e < 128; ++e) acc += q[e] * vs[e];
    ag[m] = acc * 0.08838834764831845f; // 1/sqrt(128)
}

// per-b: global MLP (64->256->256->256) then u1[b] = pm_W1[:, :256]@gs + pm_b1
__global__ void k_gmlp_u1(const float* __restrict__ invg,
                          const float* __restrict__ gmW1, const float* __restrict__ gmb1,
                          const float* __restrict__ gmW2, const float* __restrict__ gmb2,
                          const float* __restrict__ gmW3, const float* __restrict__ gmb3,
                          const float* __restrict__ pmW1, const float* __restrict__ pmb1,
                          float* __restrict__ u1g) {
    __shared__ float s_in[64];
    __shared__ float s_h[256];
    __shared__ float s_h2[256];
    int b = blockIdx.x, tid = threadIdx.x;
    if (tid < 64) s_in[tid] = invg[b*64 + tid];
    __syncthreads();
    float acc = gmb1[tid];
    #pragma unroll 4
    for (int k = 0; k < 64; k += 4) {
        float4 w = *(const float4*)&gmW1[tid*64 + k];
        acc += w.x*s_in[k] + w.y*s_in[k+1] + w.z*s_in[k+2] + w.w*s_in[k+3];
    }
    s_h[tid] = gelu_f(acc);
    __syncthreads();
    acc = gmb2[tid];
    #pragma unroll 4
    for (int i = 0; i < 256; i += 4) {
        float4 w = *(const float4*)&gmW2[tid*256 + i];
        acc += w.x*s_h[i] + w.y*s_h[i+1] + w.z*s_h[i+2] + w.w*s_h[i+3];
    }
    s_h2[tid] = gelu_f(acc);
    __syncthreads();
    acc = gmb3[tid];
    #pragma unroll 4
    for (int i = 0; i < 256; i += 4) {
        float4 w = *(const float4*)&gmW3[tid*256 + i];
        acc += w.x*s_h2[i] + w.y*s_h2[i+1] + w.z*s_h2[i+2] + w.w*s_h2[i+3];
    }
    __syncthreads();
    s_h[tid] = acc;        // global_s
    __syncthreads();
    float u = pmb1[tid];
    const float* w1 = pmW1 + tid*385;
    for (int i = 0; i < 256; ++i) u += w1[i] * s_h[i];
    u1g[b*256 + tid] = u;
}

// u2[m,j] = sum_e pm_W1[j,256+e]*query[m,e]
__global__ void k_u2(const float* __restrict__ query, const float* __restrict__ pmW1,
                     float* __restrict__ u2g) {
    __shared__ float q[128];
    int m = blockIdx.x, tid = threadIdx.x;
    if (tid < 128) q[tid] = query[m*128 + tid];
    __syncthreads();
    float acc = 0.f;
    const float* w = pmW1 + tid*385 + 256;
    for (int e = 0; e < 128; ++e) acc += w[e] * q[e];
    u2g[m*256 + tid] = acc;
}

// W2T[i,j] = pm_W2[j,i]
__global__ void k_w2t(const float* __restrict__ pmW2, float* __restrict__ w2t) {
    int o = blockIdx.x * blockDim.x + threadIdx.x; // 65536
    int i = o >> 8, j = o & 255;
    w2t[o] = pmW2[j*256 + i];
}

// Whead[c,i] = sum_j Hw[c,j]*pm_W3[j,i]  (Hw = [tW;wW;cW], 34x256)
// bhead[c]  = Hw[c,:].b3 + base bias
__global__ void k_head(const float* __restrict__ pmW3, const float* __restrict__ pmb3,
                       const float* __restrict__ tW, const float* __restrict__ tb,
                       const float* __restrict__ wW, const float* __restrict__ wb,
                       const float* __restrict__ cW, const float* __restrict__ cb,
                       float* __restrict__ wheadg, float* __restrict__ bheadg) {
    int tid = threadIdx.x;
    for (int o = tid; o < 34*256; o += 256) {
        int c = o >> 8, i = o & 255;
        const float* hw = (c < 32) ? (tW + c*256) : ((c == 32) ? wW : cW);
        float acc = 0.f;
        for (int j = 0; j < 256; ++j) acc += hw[j] * pmW3[j*256 + i];
        wheadg[o] = acc;
    }
    if (tid < 34) {
        int c = tid;
        const float* hw = (c < 32) ? (tW + c*256) : ((c == 32) ? wW : cW);
        float acc = (c < 32) ? tb[c] : ((c == 32) ? wb[0] : cb[0]);
        for (int j = 0; j < 256; ++j) acc += hw[j] * pmb3[j];
        bheadg[c] = acc;
    }
}

// ---------------- main fused kernel ----------------
// One block = 32 rows (same b, consecutive m). 8192 blocks x 256 threads.
__global__ __launch_bounds__(256, 2)
void k_main(const float* __restrict__ g, const float* __restrict__ pmW1,
            const float* __restrict__ pmb2,
            const float* __restrict__ invg, const float* __restrict__ ag,
            const float* __restrict__ u1g, const float* __restrict__ u2g,
            const float* __restrict__ w2tg, const float* __restrict__ wheadg,
            const float* __restrict__ bheadg, float* __restrict__ out) {
    __shared__ __align__(16) float h1T[9216];   // phase2: h1T[i*36+r]; later overlaid as h2s[r*260+i]
    __shared__ __align__(16) float wbuf[8840];  // phase2: W2 chunk [32][256]; phase3: Whead [34][260]
    __shared__ float invs[64];
    __shared__ float gsl[192];
    __shared__ float u1s[256];
    __shared__ float w385s[256];
    __shared__ float ainv_s[32];
    __shared__ float y0s[96];
    __shared__ float bheads[34];

    const int tid = threadIdx.x;
    const int bid = blockIdx.x;
    const int b  = bid >> 6;           // 64 blocks per b
    const int m0 = (bid & 63) << 5;    // 32 rows

    if (tid < 64)  invs[tid] = invg[b*64 + tid];
    if (tid < 192) gsl[tid]  = g[b*192 + tid];
    u1s[tid]   = u1g[b*256 + tid];
    w385s[tid] = pmW1[tid*385 + 384];
    if (tid < 34) bheads[tid] = bheadg[tid];
    __syncthreads();

    // ---- phase 1: softmax over k (rank-1 scores) ----
    if (tid < 32) {
        const int r = tid;
        const float am = ag[m0 + r];
        float mx = -1e30f;
        for (int k = 0; k < 64; ++k) mx = fmaxf(mx, invs[k]*am);
        float den = 0.f, ai = 0.f, y0 = 0.f, y1 = 0.f, y2 = 0.f;
        for (int k = 0; k < 64; ++k) {
            float e = __expf(invs[k]*am - mx);
            den += e;
            ai  += e * invs[k];
            y0  += e * gsl[k*3+0];
            y1  += e * gsl[k*3+1];
            y2  += e * gsl[k*3+2];
        }
        float id = 1.0f / den;
        ainv_s[r] = ai * id;
        y0s[r*3+0] = y0*id; y0s[r*3+1] = y1*id; y0s[r*3+2] = y2*id;
    }
    __syncthreads();

    // ---- phase 1b: h1 = gelu(u1[b] + u2[m] + ainv*w385), stored transposed ----
    {
        const float u1v = u1s[tid];
        const float wv  = w385s[tid];
        for (int r = 0; r < 32; ++r) {
            float x = u1v + u2g[(m0 + r)*256 + tid] + ainv_s[r]*wv;
            h1T[tid*36 + r] = gelu_f(x);
        }
    }
    __syncthreads();

    // ---- phase 2: h2 = gelu(H1 @ W2^T + b2), 32x256 GEMM ----
    float acc[8][4];
    #pragma unroll
    for (int rr = 0; rr < 8; ++rr)
        #pragma unroll
        for (int cc = 0; cc < 4; ++cc) acc[rr][cc] = 0.f;

    const int c0 = (tid & 63) << 2;  // 4 cols
    const int r0 = (tid >> 6) << 3;  // 8 rows (per-wave constant -> LDS broadcast)

    for (int kc = 0; kc < 8; ++kc) {
        const float4* src = (const float4*)(w2tg + kc*8192);
        float4* dst = (float4*)wbuf;
        #pragma unroll
        for (int it = 0; it < 8; ++it) dst[it*256 + tid] = src[it*256 + tid];
        __syncthreads();
        #pragma unroll
        for (int i = 0; i < 32; ++i) {
            float4 ha = *(const float4*)&h1T[(kc*32 + i)*36 + r0];
            float4 hb = *(const float4*)&h1T[(kc*32 + i)*36 + r0 + 4];
            float4 wv = *(const float4*)&wbuf[i*256 + c0];
            float h[8] = {ha.x,ha.y,ha.z,ha.w,hb.x,hb.y,hb.z,hb.w};
            float w[4] = {wv.x,wv.y,wv.z,wv.w};
            #pragma unroll
            for (int rr = 0; rr < 8; ++rr)
                #pragma unroll
                for (int cc = 0; cc < 4; ++cc)
                    acc[rr][cc] += h[rr]*w[cc];
        }
        __syncthreads();
    }

    // bias + gelu, store h2 (overlay on h1T, stride 260)
    {
        float* h2s = h1T;
        #pragma unroll
        for (int cc = 0; cc < 4; ++cc) {
            float bb = pmb2[c0 + cc];
            #pragma unroll
            for (int rr = 0; rr < 8; ++rr)
                h2s[(r0+rr)*260 + c0 + cc] = gelu_f(acc[rr][cc] + bb);
        }
    }
    // load Whead into LDS (reuse wbuf, stride 260 to dodge bank conflicts)
    for (int o = tid; o < 34*256; o += 256)
        wbuf[(o >> 8)*260 + (o & 255)] = wheadg[o];
    __syncthreads();

    // ---- phase 3: heads (34x256) + gate + writeback ----
    const float* h2s = h1T;
    for (int o = tid; o < 32*34; o += 256) {
        int r = o / 34, c = o % 34;
        float a3 = bheads[c];
        const float4* hv = (const float4*)&h2s[r*260];
        const float4* wv = (const float4*)&wbuf[c*260];
        #pragma unroll 8
        for (int i4 = 0; i4 < 64; ++i4) {
            float4 h = hv[i4], w = wv[i4];
            a3 += h.x*w.x + h.y*w.y + h.z*w.z + h.w*w.w;
        }
        size_t row = (size_t)b*2048 + (m0 + r);
        if (c < 32) {
            out[786432 + row*32 + c] = a3;
        } else if (c == 32) {
            out[786432 + 8388608 + row] = a3;
        } else {
            float gt = 1.0f / (1.0f + __expf(-a3));
            gt = fminf(fmaxf(gt, 0.0f), 1.0f);
            float* yo = out + row*3;
            yo[0] = y0s[r*3+0]*gt;
            yo[1] = y0s[r*3+1]*gt;
            yo[2] = y0s[r*3+2]*gt;
        }
    }
}

// ---------------- launcher ----------------
extern "C" void kernel_launch(void* const* d_in, const int* in_sizes, int n_in,
                              void* d_out, int out_size, void* d_ws, size_t ws_size,
                              hipStream_t stream) {
    const float* g     = (const float*)d_in[0];
    const float* query = (const float*)d_in[1];
    const float* qW    = (const float*)d_in[2];
    const float* qb    = (const float*)d_in[3];
    const float* kW    = (const float*)d_in[4];
    // d_in[5] = kb  (cancels in softmax)
    const float* gmW1  = (const float*)d_in[6];
    const float* gmb1  = (const float*)d_in[7];
    const float* gmW2  = (const float*)d_in[8];
    const float* gmb2  = (const float*)d_in[9];
    const float* gmW3  = (const float*)d_in[10];
    const float* gmb3  = (const float*)d_in[11];
    const float* pmW1  = (const float*)d_in[12];
    const float* pmb1  = (const float*)d_in[13];
    const float* pmW2  = (const float*)d_in[14];
    const float* pmb2  = (const float*)d_in[15];
    const float* pmW3  = (const float*)d_in[16];
    const float* pmb3  = (const float*)d_in[17];
    const float* tW    = (const float*)d_in[18];
    const float* tb    = (const float*)d_in[19];
    const float* wW    = (const float*)d_in[20];
    const float* wb    = (const float*)d_in[21];
    const float* cW    = (const float*)d_in[22];
    const float* cb    = (const float*)d_in[23];
    float* out = (float*)d_out;

    // workspace layout (floats), all 16B aligned
    float* ws    = (float*)d_ws;
    float* invg  = ws;            // 8192
    float* ag    = ws + 8192;     // 2048
    float* vg    = ws + 10240;    // 128
    float* s0g   = ws + 10368;    // 4 (1 used)
    float* u1g   = ws + 10496;    // 32768
    float* u2g   = ws + 43264;    // 524288
    float* w2tg  = ws + 567552;   // 65536
    float* wheadg= ws + 633088;   // 8704
    float* bheadg= ws + 641792;   // 34  (total ~642k floats = 2.57 MB)

    hipLaunchKernelGGL(k_inv,  dim3(32),   dim3(256), 0, stream, g, invg);
    hipLaunchKernelGGL(k_v,    dim3(1),    dim3(128), 0, stream, qW, qb, kW, vg, s0g);
    hipLaunchKernelGGL(k_a,    dim3(8),    dim3(256), 0, stream, query, vg, s0g, ag);
    hipLaunchKernelGGL(k_gmlp_u1, dim3(128), dim3(256), 0, stream,
                       invg, gmW1, gmb1, gmW2, gmb2, gmW3, gmb3, pmW1, pmb1, u1g);
    hipLaunchKernelGGL(k_u2,   dim3(2048), dim3(256), 0, stream, query, pmW1, u2g);
    hipLaunchKernelGGL(k_w2t,  dim3(256),  dim3(256), 0, stream, pmW2, w2tg);
    hipLaunchKernelGGL(k_head, dim3(1),    dim3(256), 0, stream,
                       pmW3, pmb3, tW, tb, wW, wb, cW, cb, wheadg, bheadg);
    hipLaunchKernelGGL(k_main, dim3(8192), dim3(256), 0, stream,
                       g, pmW1, pmb2, invg, ag, u1g, u2g, w2tg, wheadg, bheadg, out);
}

// Round 2
// 543.292 us; speedup vs baseline: 2.1833x; 2.1833x over previous
//
#include <hip/hip_runtime.h>
#include <math.h>

// B=128, K=64, M=2048, QD=128, AD=128, H=256, C=32
// out: y (786432) | type_logits (8388608) | weight_logits (262144)

typedef __attribute__((ext_vector_type(8))) short short8;
typedef __attribute__((ext_vector_type(4))) float f32x4;

__device__ __forceinline__ unsigned short bf16_rne(float f){
    union { float f; unsigned u; } v; v.f = f;
    return (unsigned short)((v.u + 0x7FFFu + ((v.u >> 16) & 1u)) >> 16);
}
__device__ __forceinline__ float bf16_tof(unsigned short h){
    union { unsigned u; float f; } v; v.u = ((unsigned)h) << 16; return v.f;
}
__device__ __forceinline__ void split_bf16(float x, unsigned short& hi, unsigned short& lo){
    hi = bf16_rne(x);
    lo = bf16_rne(x - bf16_tof(hi));
}

// Abramowitz-Stegun 7.1.26 erf (abs err 1.5e-7) -> exact-gelu to ~1e-7
__device__ __forceinline__ float gelu_f(float x){
    float z  = x * 0.70710678118654752f;
    float az = fabsf(z);
    float t  = __builtin_amdgcn_rcpf(1.0f + 0.3275911f * az);
    float p  = t*(0.254829592f + t*(-0.284496736f + t*(1.421413741f + t*(-1.453152027f + t*1.061405429f))));
    float e  = __expf(-az*az);
    float er = copysignf(1.0f - p*e, z);
    return 0.5f * x * (1.0f + er);
}

// ---------------- prep kernels ----------------

__global__ void k_inv(const float* __restrict__ g, float* __restrict__ invg) {
    int idx = blockIdx.x * blockDim.x + threadIdx.x; // 8192
    const float* p = g + idx * 3;
    invg[idx] = sqrtf(p[0]*p[0] + p[1]*p[1] + p[2]*p[2]);
}

__global__ void k_v(const float* __restrict__ qW, const float* __restrict__ qb,
                    const float* __restrict__ kW, float* __restrict__ vg,
                    float* __restrict__ s0g) {
    int e = threadIdx.x; // 128
    float acc = 0.f;
    for (int d = 0; d < 128; ++d) acc += qW[d*128 + e] * kW[d];
    vg[e] = acc;
    if (e == 0) {
        float s = 0.f;
        for (int d = 0; d < 128; ++d) s += qb[d] * kW[d];
        *s0g = s;
    }
}

__global__ void k_a(const float* __restrict__ query, const float* __restrict__ vg,
                    const float* __restrict__ s0g, float* __restrict__ ag) {
    __shared__ float vs[128];
    int tid = threadIdx.x;
    if (tid < 128) vs[tid] = vg[tid];
    __syncthreads();
    int m = blockIdx.x * blockDim.x + tid;
    const float* q = query + m * 128;
    float acc = *s0g;
    for (int e = 0; e < 128; ++e) acc += q[e] * vs[e];
    ag[m] = acc * 0.08838834764831845f; // 1/sqrt(128)
}

__global__ void k_gmlp_u1(const float* __restrict__ invg,
                          const float* __restrict__ gmW1, const float* __restrict__ gmb1,
                          const float* __restrict__ gmW2, const float* __restrict__ gmb2,
                          const float* __restrict__ gmW3, const float* __restrict__ gmb3,
                          const float* __restrict__ pmW1, const float* __restrict__ pmb1,
                          float* __restrict__ u1g) {
    __shared__ float s_in[64];
    __shared__ float s_h[256];
    __shared__ float s_h2[256];
    int b = blockIdx.x, tid = threadIdx.x;
    if (tid < 64) s_in[tid] = invg[b*64 + tid];
    __syncthreads();
    float acc = gmb1[tid];
    #pragma unroll 4
    for (int k = 0; k < 64; k += 4) {
        float4 w = *(const float4*)&gmW1[tid*64 + k];
        acc += w.x*s_in[k] + w.y*s_in[k+1] + w.z*s_in[k+2] + w.w*s_in[k+3];
    }
    s_h[tid] = gelu_f(acc);
    __syncthreads();
    acc = gmb2[tid];
    #pragma unroll 4
    for (int i = 0; i < 256; i += 4) {
        float4 w = *(const float4*)&gmW2[tid*256 + i];
        acc += w.x*s_h[i] + w.y*s_h[i+1] + w.z*s_h[i+2] + w.w*s_h[i+3];
    }
    s_h2[tid] = gelu_f(acc);
    __syncthreads();
    acc = gmb3[tid];
    #pragma unroll 4
    for (int i = 0; i < 256; i += 4) {
        float4 w = *(const float4*)&gmW3[tid*256 + i];
        acc += w.x*s_h2[i] + w.y*s_h2[i+1] + w.z*s_h2[i+2] + w.w*s_h2[i+3];
    }
    __syncthreads();
    s_h[tid] = acc;        // global_s
    __syncthreads();
    float u = pmb1[tid];
    const float* w1 = pmW1 + tid*385;
    for (int i = 0; i < 256; ++i) u += w1[i] * s_h[i];
    u1g[b*256 + tid] = u;
}

__global__ void k_u2(const float* __restrict__ query, const float* __restrict__ pmW1,
                     float* __restrict__ u2g) {
    __shared__ float q[128];
    int m = blockIdx.x, tid = threadIdx.x;
    if (tid < 128) q[tid] = query[m*128 + tid];
    __syncthreads();
    float acc = 0.f;
    const float* w = pmW1 + tid*385 + 256;
    for (int e = 0; e < 128; ++e) acc += w[e] * q[e];
    u2g[m*256 + tid] = acc;
}

// split pm_W2 ([n][k] row-major, exactly the B-operand layout) into bf16 hi/lo
__global__ void k_w2cvt(const float* __restrict__ pmW2,
                        unsigned short* __restrict__ w2h, unsigned short* __restrict__ w2l) {
    int o = blockIdx.x * 256 + threadIdx.x; // 65536
    unsigned short hi, lo; split_bf16(pmW2[o], hi, lo);
    w2h[o] = hi; w2l[o] = lo;
}

// Whead[c,:] = Hw[c,:] @ pm_W3  (Hw = [tW;wW;cW], 34x256), split bf16; bhead[c] folded bias
__global__ void k_head(const float* __restrict__ pmW3, const float* __restrict__ pmb3,
                       const float* __restrict__ tW, const float* __restrict__ tb,
                       const float* __restrict__ wW, const float* __restrict__ wb,
                       const float* __restrict__ cW, const float* __restrict__ cb,
                       unsigned short* __restrict__ wheadh, unsigned short* __restrict__ wheadl,
                       float* __restrict__ bheadg) {
    __shared__ float hw[256];
    int c = blockIdx.x;  // 0..33
    int tid = threadIdx.x;
    const float* src = (c < 32) ? (tW + c*256) : ((c == 32) ? wW : cW);
    hw[tid] = src[tid];
    __syncthreads();
    float acc = 0.f;
    for (int j = 0; j < 256; ++j) acc += hw[j] * pmW3[j*256 + tid];
    unsigned short hi, lo; split_bf16(acc, hi, lo);
    wheadh[c*256 + tid] = hi;
    wheadl[c*256 + tid] = lo;
    if (tid == 0) {
        float bacc = (c < 32) ? tb[c] : ((c == 32) ? wb[0] : cb[0]);
        for (int j = 0; j < 256; ++j) bacc += hw[j] * pmb3[j];
        bheadg[c] = bacc;
    }
}

// ---------------- main fused kernel ----------------
// One block = 32 rows (same b, consecutive m). 8192 blocks x 256 threads.
// Phase 2: h2(32x256) = gelu(H1(32x256) @ W2^T + b2) via split-bf16 MFMA.
// Phase 3: [type|weight|gate](48x32) = Whead(48x256) @ H2^T via split-bf16 MFMA.
__global__ __launch_bounds__(256, 4)
void k_main(const float* __restrict__ g,
            const float* __restrict__ invg, const float* __restrict__ ag,
            const float* __restrict__ u1g, const float* __restrict__ u2g,
            const float* __restrict__ pmW1, const float* __restrict__ pmb2,
            const unsigned short* __restrict__ w2h, const unsigned short* __restrict__ w2l,
            const unsigned short* __restrict__ wheadh, const unsigned short* __restrict__ wheadl,
            const float* __restrict__ bheadg, float* __restrict__ out) {
    // row stride 264 shorts (528 B): bank stride 4 -> worst 2-way aliasing (free)
    __shared__ __align__(16) unsigned short h1h[32*264];   // later reused as h2 hi
    __shared__ __align__(16) unsigned short h1l[32*264];   // later reused as h2 lo
    __shared__ float invs[64], gsl[192], u1s[256], w385s[256], pmb2s[256];
    __shared__ float ainv_s[32], y0s[96];

    const int tid = threadIdx.x;
    const int bid = blockIdx.x;
    const int b  = bid >> 6;
    const int m0 = (bid & 63) << 5;

    if (tid < 64)  invs[tid] = invg[b*64 + tid];
    if (tid < 192) gsl[tid]  = g[b*192 + tid];
    u1s[tid]   = u1g[b*256 + tid];
    w385s[tid] = pmW1[tid*385 + 384];
    pmb2s[tid] = pmb2[tid];
    __syncthreads();

    // ---- phase 1: rank-1 softmax over k; 8 threads per row ----
    {
        const int r = tid >> 3, sub = tid & 7;
        const float am = ag[m0 + r];
        const int kb = sub * 8;
        float mx = -1e30f;
        #pragma unroll
        for (int i = 0; i < 8; ++i) mx = fmaxf(mx, invs[kb + i] * am);
        #pragma unroll
        for (int d = 1; d < 8; d <<= 1) mx = fmaxf(mx, __shfl_xor(mx, d, 64));
        float den = 0.f, ai = 0.f, y0 = 0.f, y1 = 0.f, y2 = 0.f;
        #pragma unroll
        for (int i = 0; i < 8; ++i) {
            const int k = kb + i;
            const float iv = invs[k];
            const float e = __expf(iv * am - mx);
            den += e; ai += e * iv;
            y0 += e * gsl[k*3+0]; y1 += e * gsl[k*3+1]; y2 += e * gsl[k*3+2];
        }
        #pragma unroll
        for (int d = 1; d < 8; d <<= 1) {
            den += __shfl_xor(den, d, 64);
            ai  += __shfl_xor(ai , d, 64);
            y0  += __shfl_xor(y0 , d, 64);
            y1  += __shfl_xor(y1 , d, 64);
            y2  += __shfl_xor(y2 , d, 64);
        }
        if (sub == 0) {
            const float id = 1.0f / den;
            ainv_s[r] = ai * id;
            y0s[r*3+0] = y0*id; y0s[r*3+1] = y1*id; y0s[r*3+2] = y2*id;
        }
    }
    __syncthreads();

    // ---- phase 1b: h1 = gelu(u1[b] + u2[m] + ainv*w385) -> bf16 hi/lo in LDS ----
    {
        const int r = tid >> 3, j0 = (tid & 7) * 32;
        const float4* u2p = (const float4*)(u2g + (size_t)(m0 + r)*256 + j0);
        const float aiv = ainv_s[r];
        #pragma unroll
        for (int cjk = 0; cjk < 4; ++cjk) {
            float4 ua = u2p[cjk*2];
            float4 ub = u2p[cjk*2 + 1];
            float xs[8] = {ua.x, ua.y, ua.z, ua.w, ub.x, ub.y, ub.z, ub.w};
            short8 vh, vl;
            #pragma unroll
            for (int i = 0; i < 8; ++i) {
                const int j = j0 + cjk*8 + i;
                const float x = u1s[j] + xs[i] + aiv * w385s[j];
                const float gl = gelu_f(x);
                unsigned short hi, lo; split_bf16(gl, hi, lo);
                vh[i] = (short)hi; vl[i] = (short)lo;
            }
            *(short8*)&h1h[r*264 + j0 + cjk*8] = vh;
            *(short8*)&h1l[r*264 + j0 + cjk*8] = vl;
        }
    }
    __syncthreads();

    // ---- phase 2: 32x256x256 split-bf16 MFMA GEMM ----
    const int w  = tid >> 6, lane = tid & 63;
    const int q  = lane >> 4, ln = lane & 15;
    f32x4 acc[2][4];
    #pragma unroll
    for (int mt = 0; mt < 2; ++mt)
        #pragma unroll
        for (int nt = 0; nt < 4; ++nt) acc[mt][nt] = (f32x4){0.f,0.f,0.f,0.f};

    for (int kk = 0; kk < 8; ++kk) {
        const int kc = kk*32 + q*8;
        short8 ah0 = *(const short8*)&h1h[ ln      *264 + kc];
        short8 al0 = *(const short8*)&h1l[ ln      *264 + kc];
        short8 ah1 = *(const short8*)&h1h[(ln + 16)*264 + kc];
        short8 al1 = *(const short8*)&h1l[(ln + 16)*264 + kc];
        #pragma unroll
        for (int nt = 0; nt < 4; ++nt) {
            const int n = w*64 + nt*16 + ln;
            short8 bh = *(const short8*)&w2h[n*256 + kc];
            short8 bl = *(const short8*)&w2l[n*256 + kc];
            acc[0][nt] = __builtin_amdgcn_mfma_f32_16x16x32_bf16(ah0, bh, acc[0][nt], 0, 0, 0);
            acc[0][nt] = __builtin_amdgcn_mfma_f32_16x16x32_bf16(ah0, bl, acc[0][nt], 0, 0, 0);
            acc[0][nt] = __builtin_amdgcn_mfma_f32_16x16x32_bf16(al0, bh, acc[0][nt], 0, 0, 0);
            acc[1][nt] = __builtin_amdgcn_mfma_f32_16x16x32_bf16(ah1, bh, acc[1][nt], 0, 0, 0);
            acc[1][nt] = __builtin_amdgcn_mfma_f32_16x16x32_bf16(ah1, bl, acc[1][nt], 0, 0, 0);
            acc[1][nt] = __builtin_amdgcn_mfma_f32_16x16x32_bf16(al1, bh, acc[1][nt], 0, 0, 0);
        }
    }
    __syncthreads();  // everyone done reading h1

    // h2 = gelu(acc + b2) -> bf16 hi/lo back into the same LDS buffers
    #pragma unroll
    for (int mt = 0; mt < 2; ++mt) {
        #pragma unroll
        for (int nt = 0; nt < 4; ++nt) {
            const int n = w*64 + nt*16 + ln;
            const float bb = pmb2s[n];
            #pragma unroll
            for (int rg = 0; rg < 4; ++rg) {
                const int r = mt*16 + q*4 + rg;
                const float hv = gelu_f(acc[mt][nt][rg] + bb);
                unsigned short hi, lo; split_bf16(hv, hi, lo);
                h1h[r*264 + n] = hi;
                h1l[r*264 + n] = lo;
            }
        }
    }
    __syncthreads();

    // ---- phase 3: transposed head GEMM: D[c][r] = Whead[c,:] . h2[r,:] ----
    const int nt3 = w & 1;          // which 16-row half
    const int mtA = w >> 1;         // type-head tile 0 or 1
    const bool doB = (w < 2);       // weight/gate tile
    f32x4 accA = {0.f,0.f,0.f,0.f}, accB = {0.f,0.f,0.f,0.f};
    const int rr = nt3*16 + ln;
    const int ca = mtA*16 + ln;
    const int cb = (ln < 2) ? (32 + ln) : 33;   // clamp: rows >=34 don't exist
    for (int kk = 0; kk < 8; ++kk) {
        const int kc = kk*32 + q*8;
        short8 bh = *(const short8*)&h1h[rr*264 + kc];
        short8 bl = *(const short8*)&h1l[rr*264 + kc];
        short8 wah = *(const short8*)&wheadh[ca*256 + kc];
        short8 wal = *(const short8*)&wheadl[ca*256 + kc];
        accA = __builtin_amdgcn_mfma_f32_16x16x32_bf16(wah, bh, accA, 0, 0, 0);
        accA = __builtin_amdgcn_mfma_f32_16x16x32_bf16(wah, bl, accA, 0, 0, 0);
        accA = __builtin_amdgcn_mfma_f32_16x16x32_bf16(wal, bh, accA, 0, 0, 0);
        if (doB) {
            short8 vah = *(const short8*)&wheadh[cb*256 + kc];
            short8 val = *(const short8*)&wheadl[cb*256 + kc];
            accB = __builtin_amdgcn_mfma_f32_16x16x32_bf16(vah, bh, accB, 0, 0, 0);
            accB = __builtin_amdgcn_mfma_f32_16x16x32_bf16(vah, bl, accB, 0, 0, 0);
            accB = __builtin_amdgcn_mfma_f32_16x16x32_bf16(val, bh, accB, 0, 0, 0);
        }
    }
    {
        const size_t row = (size_t)b*2048 + m0 + rr;
        const int c0 = mtA*16 + q*4;
        f32x4 bb4 = *(const f32x4*)&bheadg[c0];
        f32x4 res = accA + bb4;
        *(f32x4*)&out[786432 + row*32 + c0] = res;
        if (doB && q == 0) {
            out[9175040 + row] = accB[0] + bheadg[32];
            float gv = accB[1] + bheadg[33];
            float gt = 1.0f / (1.0f + __expf(-gv));
            gt = fminf(fmaxf(gt, 0.0f), 1.0f);
            float* yo = out + row*3;
            yo[0] = y0s[rr*3+0] * gt;
            yo[1] = y0s[rr*3+1] * gt;
            yo[2] = y0s[rr*3+2] * gt;
        }
    }
}

// ---------------- launcher ----------------
extern "C" void kernel_launch(void* const* d_in, const int* in_sizes, int n_in,
                              void* d_out, int out_size, void* d_ws, size_t ws_size,
                              hipStream_t stream) {
    const float* g     = (const float*)d_in[0];
    const float* query = (const float*)d_in[1];
    const float* qW    = (const float*)d_in[2];
    const float* qb    = (const float*)d_in[3];
    const float* kW    = (const float*)d_in[4];
    // d_in[5] = kb (cancels in softmax)
    const float* gmW1  = (const float*)d_in[6];
    const float* gmb1  = (const float*)d_in[7];
    const float* gmW2  = (const float*)d_in[8];
    const float* gmb2  = (const float*)d_in[9];
    const float* gmW3  = (const float*)d_in[10];
    const float* gmb3  = (const float*)d_in[11];
    const float* pmW1  = (const float*)d_in[12];
    const float* pmb1  = (const float*)d_in[13];
    const float* pmW2  = (const float*)d_in[14];
    const float* pmb2  = (const float*)d_in[15];
    const float* pmW3  = (const float*)d_in[16];
    const float* pmb3  = (const float*)d_in[17];
    const float* tW    = (const float*)d_in[18];
    const float* tb    = (const float*)d_in[19];
    const float* wW    = (const float*)d_in[20];
    const float* wb    = (const float*)d_in[21];
    const float* cW    = (const float*)d_in[22];
    const float* cb    = (const float*)d_in[23];
    float* out = (float*)d_out;

    // workspace layout (float slots)
    float* ws    = (float*)d_ws;
    float* invg  = ws;                                   // 8192
    float* ag    = ws + 8192;                            // 2048
    float* vg    = ws + 10240;                           // 128
    float* s0g   = ws + 10368;                           // (pad to 10496)
    float* u1g   = ws + 10496;                           // 32768 -> 43264
    float* u2g   = ws + 43264;                           // 524288 -> 567552
    unsigned short* w2h    = (unsigned short*)(ws + 567552); // 65536 sh -> 600320
    unsigned short* w2l    = (unsigned short*)(ws + 600320); // 65536 sh -> 633088
    unsigned short* wheadh = (unsigned short*)(ws + 633088); // 8704 sh -> 637440
    unsigned short* wheadl = (unsigned short*)(ws + 637440); // 8704 sh -> 641792
    float* bheadg = ws + 641792;                         // 34

    hipLaunchKernelGGL(k_inv,     dim3(32),   dim3(256), 0, stream, g, invg);
    hipLaunchKernelGGL(k_v,       dim3(1),    dim3(128), 0, stream, qW, qb, kW, vg, s0g);
    hipLaunchKernelGGL(k_a,       dim3(8),    dim3(256), 0, stream, query, vg, s0g, ag);
    hipLaunchKernelGGL(k_gmlp_u1, dim3(128),  dim3(256), 0, stream,
                       invg, gmW1, gmb1, gmW2, gmb2, gmW3, gmb3, pmW1, pmb1, u1g);
    hipLaunchKernelGGL(k_u2,      dim3(2048), dim3(256), 0, stream, query, pmW1, u2g);
    hipLaunchKernelGGL(k_w2cvt,   dim3(256),  dim3(256), 0, stream, pmW2, w2h, w2l);
    hipLaunchKernelGGL(k_head,    dim3(34),   dim3(256), 0, stream,
                       pmW3, pmb3, tW, tb, wW, wb, cW, cb, wheadh, wheadl, bheadg);
    hipLaunchKernelGGL(k_main,    dim3(8192), dim3(256), 0, stream,
                       g, invg, ag, u1g, u2g, pmW1, pmb2,
                       w2h, w2l, wheadh, wheadl, bheadg, out);
}

// Round 3
// 288.744 us; speedup vs baseline: 4.1080x; 1.8816x over previous
//
#include <hip/hip_runtime.h>
#include <math.h>

// B=128, K=64, M=2048, QD=128, AD=128, H=256, C=32
// out: y [0,786432) | type_logits [786432,9175040) | weight_logits [9175040,9437184)

typedef __attribute__((ext_vector_type(8))) short short8;
typedef __attribute__((ext_vector_type(4))) float f32x4;

__device__ __forceinline__ unsigned short bf16_rne(float f){
    union { float f; unsigned u; } v; v.f = f;
    return (unsigned short)((v.u + 0x7FFFu + ((v.u >> 16) & 1u)) >> 16);
}

// Abramowitz-Stegun 7.1.26 erf (abs err 1.5e-7) -> exact-gelu to ~1e-7
__device__ __forceinline__ float gelu_f(float x){
    float z  = x * 0.70710678118654752f;
    float az = fabsf(z);
    float t  = __builtin_amdgcn_rcpf(1.0f + 0.3275911f * az);
    float p  = t*(0.254829592f + t*(-0.284496736f + t*(1.421413741f + t*(-1.453152027f + t*1.061405429f))));
    float e  = __expf(-az*az);
    float er = copysignf(1.0f - p*e, z);
    return 0.5f * x * (1.0f + er);
}

// ---------------- fused prep kernel 1 ----------------
// blocks [0,32): inv | 32: v,s0 | [33,97): w2->bf16 | [97,131): head fold | [131,643): u2 (4 m/blk)
__global__ void k_pre1(const float* __restrict__ g, const float* __restrict__ qW,
                       const float* __restrict__ qb, const float* __restrict__ kW,
                       const float* __restrict__ query, const float* __restrict__ pmW1,
                       const float* __restrict__ pmW2, const float* __restrict__ pmW3,
                       const float* __restrict__ pmb3,
                       const float* __restrict__ tW, const float* __restrict__ tb,
                       const float* __restrict__ wW, const float* __restrict__ wb,
                       const float* __restrict__ cW, const float* __restrict__ cb,
                       float* __restrict__ invg, float* __restrict__ vg, float* __restrict__ s0g,
                       unsigned short* __restrict__ w2b, unsigned short* __restrict__ wheadb,
                       float* __restrict__ bheadg, float* __restrict__ u2g) {
    const int bid = blockIdx.x, tid = threadIdx.x;
    if (bid < 32) {
        int idx = bid*256 + tid;
        const float* p = g + idx*3;
        invg[idx] = sqrtf(p[0]*p[0] + p[1]*p[1] + p[2]*p[2]);
    } else if (bid == 32) {
        if (tid < 128) {
            float acc = 0.f;
            for (int d = 0; d < 128; ++d) acc += qW[d*128 + tid] * kW[d];
            vg[tid] = acc;
            if (tid == 0) {
                float s = 0.f;
                for (int d = 0; d < 128; ++d) s += qb[d] * kW[d];
                *s0g = s;
            }
        }
    } else if (bid < 97) {
        int o = (bid - 33)*1024 + tid*4;
        float4 x = *(const float4*)&pmW2[o];
        union { unsigned short u[4]; uint2 v; } r;
        r.u[0] = bf16_rne(x.x); r.u[1] = bf16_rne(x.y);
        r.u[2] = bf16_rne(x.z); r.u[3] = bf16_rne(x.w);
        *(uint2*)&w2b[o] = r.v;
    } else if (bid < 131) {
        __shared__ float hw[256];
        int c = bid - 97;
        const float* src = (c < 32) ? (tW + c*256) : ((c == 32) ? wW : cW);
        hw[tid] = src[tid];
        __syncthreads();
        float acc = 0.f;
        for (int j = 0; j < 256; ++j) acc += hw[j] * pmW3[j*256 + tid];
        wheadb[c*256 + tid] = bf16_rne(acc);
        if (tid == 0) {
            float bacc = (c < 32) ? tb[c] : ((c == 32) ? wb[0] : cb[0]);
            for (int j = 0; j < 256; ++j) bacc += hw[j] * pmb3[j];
            bheadg[c] = bacc;
        }
    } else {
        // u2[m,j] = pm_W1[j,256:384] . query[m]  for 4 consecutive m
        __shared__ float qv[4][128];
        int mbase = (bid - 131)*4;
        if (tid < 128) {
            #pragma unroll
            for (int mm = 0; mm < 4; ++mm) qv[mm][tid] = query[(mbase+mm)*128 + tid];
        }
        __syncthreads();
        const float* wp = pmW1 + tid*385 + 256;   // 4B-aligned only (stride 385)
        float a0=0.f, a1=0.f, a2=0.f, a3=0.f;
        for (int e = 0; e < 128; ++e) {
            float wv = wp[e];
            a0 += wv*qv[0][e]; a1 += wv*qv[1][e];
            a2 += wv*qv[2][e]; a3 += wv*qv[3][e];
        }
        u2g[(mbase+0)*256 + tid] = a0;
        u2g[(mbase+1)*256 + tid] = a1;
        u2g[(mbase+2)*256 + tid] = a2;
        u2g[(mbase+3)*256 + tid] = a3;
    }
}

// ---------------- fused prep kernel 2 ----------------
// blocks [0,8): a[m] | [8,136): global-MLP + u1 fold
__global__ void k_pre2(const float* __restrict__ query, const float* __restrict__ vg,
                       const float* __restrict__ s0g, const float* __restrict__ invg,
                       const float* __restrict__ gmW1, const float* __restrict__ gmb1,
                       const float* __restrict__ gmW2, const float* __restrict__ gmb2,
                       const float* __restrict__ gmW3, const float* __restrict__ gmb3,
                       const float* __restrict__ pmW1, const float* __restrict__ pmb1,
                       float* __restrict__ ag, float* __restrict__ u1g) {
    const int bid = blockIdx.x, tid = threadIdx.x;
    if (bid < 8) {
        __shared__ float vs[128];
        if (tid < 128) vs[tid] = vg[tid];
        __syncthreads();
        int m = bid*256 + tid;
        const float4* qp = (const float4*)(query + m*128);
        float acc = *s0g;
        #pragma unroll 8
        for (int e4 = 0; e4 < 32; ++e4) {
            float4 q = qp[e4];
            acc += q.x*vs[e4*4] + q.y*vs[e4*4+1] + q.z*vs[e4*4+2] + q.w*vs[e4*4+3];
        }
        ag[m] = acc * 0.08838834764831845f; // 1/sqrt(128)
    } else {
        __shared__ float s_in[64];
        __shared__ float s_h[256];
        __shared__ float s_h2[256];
        int b = bid - 8;
        if (tid < 64) s_in[tid] = invg[b*64 + tid];
        __syncthreads();
        float acc = gmb1[tid];
        #pragma unroll 4
        for (int k = 0; k < 64; k += 4) {
            float4 w = *(const float4*)&gmW1[tid*64 + k];
            acc += w.x*s_in[k] + w.y*s_in[k+1] + w.z*s_in[k+2] + w.w*s_in[k+3];
        }
        s_h[tid] = gelu_f(acc);
        __syncthreads();
        acc = gmb2[tid];
        #pragma unroll 4
        for (int i = 0; i < 256; i += 4) {
            float4 w = *(const float4*)&gmW2[tid*256 + i];
            acc += w.x*s_h[i] + w.y*s_h[i+1] + w.z*s_h[i+2] + w.w*s_h[i+3];
        }
        s_h2[tid] = gelu_f(acc);
        __syncthreads();
        acc = gmb3[tid];
        #pragma unroll 4
        for (int i = 0; i < 256; i += 4) {
            float4 w = *(const float4*)&gmW3[tid*256 + i];
            acc += w.x*s_h2[i] + w.y*s_h2[i+1] + w.z*s_h2[i+2] + w.w*s_h2[i+3];
        }
        __syncthreads();
        s_h[tid] = acc;        // global_s
        __syncthreads();
        float u = pmb1[tid];
        const float* w1 = pmW1 + tid*385;
        for (int i = 0; i < 256; ++i) u += w1[i] * s_h[i];
        u1g[b*256 + tid] = u;
    }
}

// ---------------- main fused kernel ----------------
// One block = 64 rows (same b). 4096 blocks x 256 threads. Pure bf16 MFMA.
__global__ __launch_bounds__(256, 4)
void k_main(const float* __restrict__ g,
            const float* __restrict__ invg, const float* __restrict__ ag,
            const float* __restrict__ u1g, const float* __restrict__ u2g,
            const float* __restrict__ pmW1, const float* __restrict__ pmb2,
            const unsigned short* __restrict__ w2b, const unsigned short* __restrict__ wheadb,
            const float* __restrict__ bheadg, float* __restrict__ out) {
    // row stride 264 shorts (528 B): dword-stride 132 == 4 (mod 32) -> worst 2-way (free)
    __shared__ __align__(16) unsigned short hb[64*264];  // h1, later h2
    __shared__ float invs[64], gsl[192], u1s[256], w385s[256], pmb2s[256];
    __shared__ float ainv_s[64], y0s[192];

    const int tid = threadIdx.x;
    const int bid = blockIdx.x;
    const int b  = bid >> 5;           // 32 tiles per b
    const int m0 = (bid & 31) << 6;    // 64 rows

    if (tid < 64)  invs[tid] = invg[b*64 + tid];
    if (tid < 192) gsl[tid]  = g[b*192 + tid];
    u1s[tid]   = u1g[b*256 + tid];
    w385s[tid] = pmW1[tid*385 + 384];
    pmb2s[tid] = pmb2[tid];
    __syncthreads();

    // ---- phase 1: rank-1 softmax over k; 4 threads per row ----
    {
        const int r = tid >> 2, sub = tid & 3;
        const float am = ag[m0 + r];
        const int kb = sub * 16;
        float mx = -1e30f;
        #pragma unroll
        for (int i = 0; i < 16; ++i) mx = fmaxf(mx, invs[kb + i] * am);
        #pragma unroll
        for (int d = 1; d < 4; d <<= 1) mx = fmaxf(mx, __shfl_xor(mx, d, 64));
        float den = 0.f, ai = 0.f, y0 = 0.f, y1 = 0.f, y2 = 0.f;
        #pragma unroll
        for (int i = 0; i < 16; ++i) {
            const int k = kb + i;
            const float iv = invs[k];
            const float e = __expf(iv * am - mx);
            den += e; ai += e * iv;
            y0 += e * gsl[k*3+0]; y1 += e * gsl[k*3+1]; y2 += e * gsl[k*3+2];
        }
        #pragma unroll
        for (int d = 1; d < 4; d <<= 1) {
            den += __shfl_xor(den, d, 64);
            ai  += __shfl_xor(ai , d, 64);
            y0  += __shfl_xor(y0 , d, 64);
            y1  += __shfl_xor(y1 , d, 64);
            y2  += __shfl_xor(y2 , d, 64);
        }
        if (sub == 0) {
            const float id = 1.0f / den;
            ainv_s[r] = ai * id;
            y0s[r*3+0] = y0*id; y0s[r*3+1] = y1*id; y0s[r*3+2] = y2*id;
        }
    }
    __syncthreads();

    const int w = tid >> 6, lane = tid & 63;

    // ---- phase 1b: h1 = gelu(u1[b] + u2[m] + ainv*w385) -> bf16 LDS ----
    // row = lane (2-way LDS write aliasing only), cols w*64..w*64+63
    {
        const int r = lane, j0 = w * 64;
        const float aiv = ainv_s[r];
        const float4* u2p = (const float4*)(u2g + (size_t)(m0 + r)*256 + j0);
        #pragma unroll
        for (int c8 = 0; c8 < 8; ++c8) {
            float4 ua = u2p[c8*2];
            float4 ub = u2p[c8*2 + 1];
            float xs[8] = {ua.x, ua.y, ua.z, ua.w, ub.x, ub.y, ub.z, ub.w};
            short8 vh;
            #pragma unroll
            for (int i = 0; i < 8; ++i) {
                const int j = j0 + c8*8 + i;
                const float x = u1s[j] + xs[i] + aiv * w385s[j];
                vh[i] = (short)bf16_rne(gelu_f(x));
            }
            *(short8*)&hb[r*264 + j0 + c8*8] = vh;
        }
    }
    __syncthreads();

    // ---- phase 2: 64x256x256 bf16 MFMA GEMM (wave w owns cols w*64..+63, all rows) ----
    const int q = lane >> 4, ln = lane & 15;
    f32x4 acc[4][4];
    #pragma unroll
    for (int mt = 0; mt < 4; ++mt)
        #pragma unroll
        for (int nt = 0; nt < 4; ++nt) acc[mt][nt] = (f32x4){0.f,0.f,0.f,0.f};

    #pragma unroll 2
    for (int kk = 0; kk < 8; ++kk) {
        const int kc = kk*32 + q*8;
        short8 afrag[4], bfrag[4];
        #pragma unroll
        for (int mt = 0; mt < 4; ++mt)
            afrag[mt] = *(const short8*)&hb[(mt*16 + ln)*264 + kc];
        #pragma unroll
        for (int nt = 0; nt < 4; ++nt)
            bfrag[nt] = *(const short8*)&w2b[(w*64 + nt*16 + ln)*256 + kc];
        #pragma unroll
        for (int mt = 0; mt < 4; ++mt)
            #pragma unroll
            for (int nt = 0; nt < 4; ++nt)
                acc[mt][nt] = __builtin_amdgcn_mfma_f32_16x16x32_bf16(afrag[mt], bfrag[nt], acc[mt][nt], 0, 0, 0);
    }
    __syncthreads();

    // h2 = gelu(acc + b2) -> bf16 back into hb
    #pragma unroll
    for (int mt = 0; mt < 4; ++mt) {
        #pragma unroll
        for (int nt = 0; nt < 4; ++nt) {
            const int n = w*64 + nt*16 + ln;
            const float bb = pmb2s[n];
            #pragma unroll
            for (int rg = 0; rg < 4; ++rg) {
                const int r = mt*16 + q*4 + rg;
                hb[r*264 + n] = bf16_rne(gelu_f(acc[mt][nt][rg] + bb));
            }
        }
    }
    __syncthreads();

    // ---- phase 3: heads: D[c][r] = Whead[c,:] . h2[r,:]; wave w owns rows w*16..+15 ----
    f32x4 accA0 = {0.f,0.f,0.f,0.f}, accA1 = {0.f,0.f,0.f,0.f}, accB = {0.f,0.f,0.f,0.f};
    const int rr = w*16 + ln;
    const int cb2 = (ln < 2) ? (32 + ln) : 33;   // rows >=34 don't exist
    #pragma unroll 2
    for (int kk = 0; kk < 8; ++kk) {
        const int kc = kk*32 + q*8;
        short8 bh = *(const short8*)&hb[rr*264 + kc];
        short8 a0 = *(const short8*)&wheadb[ ln      *256 + kc];
        short8 a1 = *(const short8*)&wheadb[(16 + ln)*256 + kc];
        short8 a2 = *(const short8*)&wheadb[ cb2     *256 + kc];
        accA0 = __builtin_amdgcn_mfma_f32_16x16x32_bf16(a0, bh, accA0, 0, 0, 0);
        accA1 = __builtin_amdgcn_mfma_f32_16x16x32_bf16(a1, bh, accA1, 0, 0, 0);
        accB  = __builtin_amdgcn_mfma_f32_16x16x32_bf16(a2, bh, accB , 0, 0, 0);
    }
    {
        const size_t row = (size_t)b*2048 + m0 + rr;
        const int c0 = q*4;
        f32x4 r0 = accA0 + *(const f32x4*)&bheadg[c0];
        f32x4 r1 = accA1 + *(const f32x4*)&bheadg[16 + c0];
        *(f32x4*)&out[786432 + row*32 + c0]      = r0;
        *(f32x4*)&out[786432 + row*32 + 16 + c0] = r1;
        if (q == 0) {
            out[9175040 + row] = accB[0] + bheadg[32];
            float gv = accB[1] + bheadg[33];
            float gt = 1.0f / (1.0f + __expf(-gv));
            gt = fminf(fmaxf(gt, 0.0f), 1.0f);
            float* yo = out + row*3;
            yo[0] = y0s[rr*3+0] * gt;
            yo[1] = y0s[rr*3+1] * gt;
            yo[2] = y0s[rr*3+2] * gt;
        }
    }
}

// ---------------- launcher ----------------
extern "C" void kernel_launch(void* const* d_in, const int* in_sizes, int n_in,
                              void* d_out, int out_size, void* d_ws, size_t ws_size,
                              hipStream_t stream) {
    const float* g     = (const float*)d_in[0];
    const float* query = (const float*)d_in[1];
    const float* qW    = (const float*)d_in[2];
    const float* qb    = (const float*)d_in[3];
    const float* kW    = (const float*)d_in[4];
    // d_in[5] = kb (cancels in softmax)
    const float* gmW1  = (const float*)d_in[6];
    const float* gmb1  = (const float*)d_in[7];
    const float* gmW2  = (const float*)d_in[8];
    const float* gmb2  = (const float*)d_in[9];
    const float* gmW3  = (const float*)d_in[10];
    const float* gmb3  = (const float*)d_in[11];
    const float* pmW1  = (const float*)d_in[12];
    const float* pmb1  = (const float*)d_in[13];
    const float* pmW2  = (const float*)d_in[14];
    const float* pmb2  = (const float*)d_in[15];
    const float* pmW3  = (const float*)d_in[16];
    const float* pmb3  = (const float*)d_in[17];
    const float* tW    = (const float*)d_in[18];
    const float* tb    = (const float*)d_in[19];
    const float* wW    = (const float*)d_in[20];
    const float* wb    = (const float*)d_in[21];
    const float* cW    = (const float*)d_in[22];
    const float* cb    = (const float*)d_in[23];
    float* out = (float*)d_out;

    // workspace layout (float slots)
    float* ws    = (float*)d_ws;
    float* invg  = ws;                                      // 8192
    float* ag    = ws + 8192;                               // 2048
    float* vg    = ws + 10240;                              // 128
    float* s0g   = ws + 10368;                              // pad -> 10496
    float* u1g   = ws + 10496;                              // 32768 -> 43264
    float* u2g   = ws + 43264;                              // 524288 -> 567552
    unsigned short* w2b    = (unsigned short*)(ws + 567552); // 65536 sh -> 600320
    unsigned short* wheadb = (unsigned short*)(ws + 600320); // 8704 sh -> 604672
    float* bheadg = ws + 604672;                            // 34

    hipLaunchKernelGGL(k_pre1, dim3(643), dim3(256), 0, stream,
                       g, qW, qb, kW, query, pmW1, pmW2, pmW3, pmb3,
                       tW, tb, wW, wb, cW, cb,
                       invg, vg, s0g, w2b, wheadb, bheadg, u2g);
    hipLaunchKernelGGL(k_pre2, dim3(136), dim3(256), 0, stream,
                       query, vg, s0g, invg,
                       gmW1, gmb1, gmW2, gmb2, gmW3, gmb3, pmW1, pmb1,
                       ag, u1g);
    hipLaunchKernelGGL(k_main, dim3(4096), dim3(256), 0, stream,
                       g, invg, ag, u1g, u2g, pmW1, pmb2,
                       w2b, wheadb, bheadg, out);
}